// Round 5
// baseline (696.270 us; speedup 1.0000x reference)
//
#include <hip/hip_runtime.h>
#include <hip/hip_bf16.h>

// MultiHeadAttentionBlock: B=4, S=2048, D=512, H=8, DK=64, causal.
// R15: R14 single persistent kernel, relaunched SAFELY.
//      R14 hung (container died twice): plain launch + manual "768 = 3/CU"
//      co-residency arithmetic => gbar deadlock if any block isn't resident.
//      Fix: (1) hipLaunchCooperativeKernel - runtime VALIDATES grid fits
//      co-resident => atomic barriers deadlock-free by construction;
//      (2) if the cooperative launch errors, fall back to the verified
//      4-kernel chain (same device bodies) => worst case ~199us, never hang;
//      (3) gbar hardened with __threadfence before the release-add.
//      Phases (as R14): 0 cvt weights/biases; 1 qkv GEMM (A fp32 staged
//      directly via global_load_lds, bf16 convert at LDS-read; kills the
//      72MB activation-cvt round-trip); 2 attn (R10 inner loop, per-CU
//      exactly 66 kv-iters); 3 oproj 64x64.

#define BATCH  4
#define SLEN   2048
#define DMODEL 512
#define NHEAD  8
#define DHEAD  64
#define MROWS  (BATCH * SLEN)   // 8192

#define NQ ((size_t)MROWS * DMODEL)     // 4194304
#define NW ((size_t)DMODEL * DMODEL)    // 262144
#define NB ((size_t)DMODEL)             // 512
#define CVTW_TOTAL (4 * NW + 4 * NB)    // 1050624

#define GRID_P 768                      // 3 blocks/CU * 256 CUs (validated by coop launch)

#define SCALE_L2E 0.180336880f          // (1/8) * log2(e)

typedef short bf16x8 __attribute__((ext_vector_type(8)));
typedef float f32x4  __attribute__((ext_vector_type(4)));

typedef unsigned int __attribute__((address_space(1))) glb_u32_t;
typedef unsigned int __attribute__((address_space(3))) lds_u32_t;

__device__ __forceinline__ void async16(const void* g, void* l) {
    // 16B per lane, HW writes LDS at wave-uniform base + lane*16
    __builtin_amdgcn_global_load_lds((glb_u32_t*)g, (lds_u32_t*)l, 16, 0, 0);
}

__device__ __forceinline__ float bf2f(unsigned short u) {
    union { unsigned int i; float f; } v; v.i = ((unsigned int)u) << 16; return v.f;
}
__device__ __forceinline__ unsigned short f2bf(float f) {
    union { float f; unsigned int i; } v; v.f = f;
    unsigned int x = v.i;
    return (unsigned short)((x + 0x7fffu + ((x >> 16) & 1u)) >> 16);
}
__device__ __forceinline__ unsigned int pkbf(float a, float b) {
    union { __hip_bfloat162 h; unsigned int u; } cv;
    cv.h = __float22bfloat162_rn(float2{a, b});
    return cv.u;
}

__device__ __forceinline__ void wait0_barrier() {
    asm volatile("s_waitcnt vmcnt(0)" ::: "memory");
    __builtin_amdgcn_s_barrier();
    asm volatile("" ::: "memory");
}

// Grid barrier among co-resident blocks (cooperative launch guarantees
// residency). __syncthreads (each wave drains its own vmem) -> tid0
// device fence + release-add -> acquire-spin -> __syncthreads.
__device__ __forceinline__ void gbar(unsigned* c) {
    __syncthreads();
    if (threadIdx.x == 0) {
        __threadfence();
        __hip_atomic_fetch_add(c, 1u, __ATOMIC_RELEASE, __HIP_MEMORY_SCOPE_AGENT);
        while (__hip_atomic_load(c, __ATOMIC_ACQUIRE, __HIP_MEMORY_SCOPE_AGENT) < gridDim.x)
            __builtin_amdgcn_s_sleep(8);
    }
    __syncthreads();
}

// ---------------- qkv GEMM body: C[M,512] = A_fp32 * W_bf16^T + b ----------------
// 128x128 tile, BK=32, 4 waves -> 64x64 each. A staged fp32 via gload_lds
// (dbuf 32KB, rows of 8 16B-chunks, phys = logical ^ (row&7)); converted to
// bf16 at LDS-read. W bf16 via gload_lds (rows of 4 chunks, phys = logical ^
// (row&3)). One barrier per K-iter. mode: 0=Q(scaled) 1=K 2=V^T store.
__device__ __forceinline__ void qkv_body(const float* __restrict__ A,
                                         const unsigned short* __restrict__ W,
                                         const unsigned short* __restrict__ bias,
                                         unsigned short* __restrict__ C,
                                         int mode, int m0, int n0,
                                         unsigned char* smem)
{
    float*          Asf = (float*)smem;                          // [2][128*32] f32 32KB
    unsigned short* Bs  = (unsigned short*)(smem + 32768);       // [2][128*32] bf16 16KB

    const int tid  = threadIdx.x;
    const int wave = tid >> 6;
    const int lane = tid & 63;
    const int l15  = lane & 15;
    const int quad = lane >> 4;
    const int wm   = (wave & 1) * 64;
    const int wn   = (wave >> 1) * 64;
    const int srow = lane >> 2;                         // W staging: 0..15
    const int scol = (((lane & 3) ^ (srow & 3)) * 8);   // W swizzled col (bf16)
    const int rswb = (quad ^ (l15 & 3)) * 8;            // W read swizzle
    const int krow = lane >> 3;                         // A staging: 0..7
    const int acol = ((lane & 7) ^ (krow & 7)) * 4;     // A swizzled col (f32)

    auto stageA = [&](int k0, int buf) {
        #pragma unroll
        for (int c = 0; c < 4; c++) {
            const int rb = c * 32 + wave * 8;
            async16(A + (size_t)(m0 + rb + krow) * DMODEL + k0 + acol,
                    Asf + (size_t)buf * 4096 + rb * 32);
        }
    };
    auto stageW = [&](int k0, int buf) {
        async16(W + (size_t)(n0 + wave * 16 + srow) * DMODEL + k0 + scol,
                Bs + (size_t)buf * 4096 + wave * 512);
        async16(W + (size_t)(n0 + (wave + 4) * 16 + srow) * DMODEL + k0 + scol,
                Bs + (size_t)buf * 4096 + (wave + 4) * 512);
    };

    f32x4 acc[4][4] = {};
    stageA(0, 0);
    stageW(0, 0);

    #pragma unroll 1
    for (int kt = 0; kt < 16; kt++) {
        const int cur = kt & 1;
        wait0_barrier();
        if (kt < 15) { stageA((kt + 1) * 32, cur ^ 1); stageW((kt + 1) * 32, cur ^ 1); }

        bf16x8 af[4], bfr[4];
        #pragma unroll
        for (int i = 0; i < 4; i++) {
            const int row = wm + i * 16 + l15;
            const float* rp = Asf + (size_t)cur * 4096 + row * 32;
            const f32x4 x = *(const f32x4*)(rp + (((quad * 2)     ^ (row & 7)) * 4));
            const f32x4 y = *(const f32x4*)(rp + (((quad * 2 + 1) ^ (row & 7)) * 4));
            union { bf16x8 v; unsigned int u[4]; } r;
            r.u[0] = pkbf(x[0], x[1]); r.u[1] = pkbf(x[2], x[3]);
            r.u[2] = pkbf(y[0], y[1]); r.u[3] = pkbf(y[2], y[3]);
            af[i] = r.v;
        }
        #pragma unroll
        for (int j = 0; j < 4; j++)
            bfr[j] = *(const bf16x8*)(Bs + (size_t)cur * 4096 + (wn + j * 16 + l15) * 32 + rswb);
        #pragma unroll
        for (int i = 0; i < 4; i++)
            #pragma unroll
            for (int j = 0; j < 4; j++)
                acc[i][j] = __builtin_amdgcn_mfma_f32_16x16x32_bf16(af[i], bfr[j], acc[i][j], 0, 0, 0);
    }

    // epilogue: C/D layout col = lane&15, row = quad*4 + reg
    if (mode == 2) {
        // V^T store: col -> (h,dk), row -> (b,s)
        #pragma unroll
        for (int j = 0; j < 4; j++) {
            const int col = n0 + wn + j * 16 + l15;
            const float bv = bf2f(bias[col]);
            const int hh = col >> 6, dk = col & 63;
            #pragma unroll
            for (int i = 0; i < 4; i++) {
                const int row = m0 + wm + i * 16 + quad * 4;
                const int bb = row >> 11, s = row & 2047;
                uint2 o2;
                o2.x = pkbf(acc[i][j][0] + bv, acc[i][j][1] + bv);
                o2.y = pkbf(acc[i][j][2] + bv, acc[i][j][3] + bv);
                *(uint2*)(C + ((size_t)((bb * NHEAD + hh) * DHEAD + dk)) * SLEN + s) = o2;
            }
        }
    } else {
        const float oscale = (mode == 0) ? SCALE_L2E : 1.0f;
        #pragma unroll
        for (int j = 0; j < 4; j++) {
            const int col = n0 + wn + j * 16 + l15;
            const float bv = bf2f(bias[col]);
            #pragma unroll
            for (int i = 0; i < 4; i++) {
                const int row = m0 + wm + i * 16 + quad * 4;
                #pragma unroll
                for (int r = 0; r < 4; r++)
                    C[(size_t)(row + r) * DMODEL + col] = f2bf((acc[i][j][r] + bv) * oscale);
            }
        }
    }
}

// ---------------- Flash attention body (R10 inner structure) ----------------
// One 64-row q-tile of one (b,h); 4 waves x 16 q. KV tiles of 64 staged via
// gload_lds into XOR-chunk-swizzled double buffers; one barrier/iter.
// Q pre-scaled by (1/8)log2e; fixed-reference softmax p = exp2(s).
// LDS: Ks 16K + Vs 16K + Ps 8K = 40960 B.
__device__ __forceinline__ void attn_body(const unsigned short* __restrict__ qh,
                                          const unsigned short* __restrict__ kh,
                                          const unsigned short* __restrict__ vt,
                                          unsigned short* __restrict__ ctx,
                                          int bh, int qt, unsigned char* smem)
{
    unsigned short* Ks = (unsigned short*)smem;       // [2][64*64]
    unsigned short* Vs = Ks + 2 * 64 * 64;            // [2][64*64]
    unsigned short* Ps = Vs + 2 * 64 * 64;            // [4][16*64]

    const int tid  = threadIdx.x;
    const int wave = tid >> 6;
    const int lane = tid & 63;
    const int l15  = lane & 15;
    const int quad = lane >> 4;
    const int b = bh >> 3, h = bh & 7;

    const size_t base = (size_t)b * SLEN * DMODEL + (size_t)h * DHEAD;
    const unsigned short* Q  = qh + base;
    const unsigned short* K  = kh + base;
    const unsigned short* VT = vt + (size_t)bh * DHEAD * SLEN;

    const int krow_l = lane >> 3;
    const int kcol_l = ((lane & 7) ^ (krow_l & 7)) * 8;

    const int qrow = qt * 64 + wave * 16 + l15;
    const bf16x8 qf0 = *(const bf16x8*)(Q + (size_t)qrow * DMODEL + quad * 8);
    const bf16x8 qf1 = *(const bf16x8*)(Q + (size_t)qrow * DMODEL + 32 + quad * 8);

    f32x4 oacc[4] = {};
    float lsum = 0.0f;
    unsigned short* Pw = Ps + wave * (16 * 64);
    const int ktiles = qt + 1;

    auto stageKV = [&](int kt, int buf) {
        async16(K + (size_t)(kt * 64 + wave * 8 + krow_l) * DMODEL + kcol_l,
                Ks + (size_t)buf * 4096 + wave * 512);
        async16(K + (size_t)(kt * 64 + (wave + 4) * 8 + krow_l) * DMODEL + kcol_l,
                Ks + (size_t)buf * 4096 + (wave + 4) * 512);
        async16(VT + (size_t)(wave * 8 + krow_l) * SLEN + kt * 64 + kcol_l,
                Vs + (size_t)buf * 4096 + wave * 512);
        async16(VT + (size_t)((wave + 4) * 8 + krow_l) * SLEN + kt * 64 + kcol_l,
                Vs + (size_t)buf * 4096 + (wave + 4) * 512);
    };

    stageKV(0, 0);

    #pragma unroll 1
    for (int kt = 0; kt < ktiles; kt++) {
        const int cur = kt & 1;
        wait0_barrier();
        if (kt + 1 < ktiles) stageKV(kt + 1, cur ^ 1);

        // S^T = K Q^T
        f32x4 sacc[4] = {};
        #pragma unroll
        for (int kk = 0; kk < 2; kk++) {
            const bf16x8 qf = kk ? qf1 : qf0;
            #pragma unroll
            for (int j = 0; j < 4; j++) {
                bf16x8 kf = *(const bf16x8*)(Ks + (size_t)cur * 4096 + (j * 16 + l15) * 64
                                                + (((kk * 4 + quad) ^ (l15 & 7)) * 8));
                sacc[j] = __builtin_amdgcn_mfma_f32_16x16x32_bf16(kf, qf, sacc[j], 0, 0, 0);
            }
        }

        if (kt == qt) {   // causal mask: diagonal tile only
            #pragma unroll
            for (int j = 0; j < 4; j++)
                #pragma unroll
                for (int r = 0; r < 4; r++) {
                    const int kv = kt * 64 + j * 16 + quad * 4 + r;
                    if (kv > qrow) sacc[j][r] = -1e30f;
                }
        }

        // p = exp2(s); accumulate l; pack P^T -> Ps[q][kv] (XOR chunk swizzle)
        #pragma unroll
        for (int j = 0; j < 4; j++) {
            const float p0 = exp2f(sacc[j][0]);
            const float p1 = exp2f(sacc[j][1]);
            const float p2v = exp2f(sacc[j][2]);
            const float p3 = exp2f(sacc[j][3]);
            lsum += (p0 + p1) + (p2v + p3);
            uint2 pw;
            pw.x = pkbf(p0, p1);
            pw.y = pkbf(p2v, p3);
            const int chunk = (j * 2 + (quad >> 1)) ^ (l15 & 7);
            *(uint2*)(Pw + l15 * 64 + chunk * 8 + (quad & 1) * 4) = pw;
        }
        asm volatile("s_waitcnt lgkmcnt(0)" ::: "memory");

        // O^T += V^T P^T
        #pragma unroll
        for (int kk = 0; kk < 2; kk++) {
            bf16x8 pf = *(const bf16x8*)(Pw + l15 * 64 + (((kk * 4 + quad) ^ (l15 & 7)) * 8));
            #pragma unroll
            for (int jd = 0; jd < 4; jd++) {
                bf16x8 vf = *(const bf16x8*)(Vs + (size_t)cur * 4096 + (jd * 16 + l15) * 64
                                                + (((kk * 4 + quad) ^ (l15 & 7)) * 8));
                oacc[jd] = __builtin_amdgcn_mfma_f32_16x16x32_bf16(vf, pf, oacc[jd], 0, 0, 0);
            }
        }
    }

    lsum += __shfl_xor(lsum, 16, 64);
    lsum += __shfl_xor(lsum, 32, 64);
    const float invl = 1.0f / lsum;

    #pragma unroll
    for (int jd = 0; jd < 4; jd++) {
        uint2 o2;
        o2.x = pkbf(oacc[jd][0] * invl, oacc[jd][1] * invl);
        o2.y = pkbf(oacc[jd][2] * invl, oacc[jd][3] * invl);
        *(uint2*)(ctx + base + (size_t)qrow * DMODEL + jd * 16 + quad * 4) = o2;
    }
}

// ---------------- oproj body: out[M,512] = ctx_bf16 * Wo^T + bo ----------------
// 64x64 tile, 4 waves -> 32x32 each. LDS 16KB dbuf, gload_lds, XOR swizzle.
__device__ __forceinline__ void oproj_body(const unsigned short* __restrict__ ctx,
                                           const unsigned short* __restrict__ wo,
                                           const unsigned short* __restrict__ bo,
                                           float* __restrict__ out,
                                           int m0, int n0, unsigned char* smem)
{
    unsigned short* As = (unsigned short*)smem;   // [2][64*32]
    unsigned short* Bs = As + 2 * 64 * 32;        // [2][64*32]

    const int tid  = threadIdx.x;
    const int wave = tid >> 6;
    const int lane = tid & 63;
    const int l15  = lane & 15;
    const int quad = lane >> 4;
    const int wm   = (wave & 1) * 32;
    const int wn   = (wave >> 1) * 32;
    const int srow = lane >> 2;
    const int scol = (((lane & 3) ^ (srow & 3)) * 8);
    const int rsw  = (quad ^ (l15 & 3)) * 8;

    auto stage = [&](int k0, int buf) {
        async16(ctx + (size_t)(m0 + wave * 16 + srow) * DMODEL + k0 + scol,
                As + (size_t)buf * 2048 + wave * 512);
        async16(wo + (size_t)(n0 + wave * 16 + srow) * DMODEL + k0 + scol,
                Bs + (size_t)buf * 2048 + wave * 512);
    };

    f32x4 acc[2][2] = {};
    stage(0, 0);

    #pragma unroll 1
    for (int kt = 0; kt < 16; kt++) {
        const int cur = kt & 1;
        wait0_barrier();
        if (kt < 15) stage((kt + 1) * 32, cur ^ 1);

        bf16x8 af[2], bfr[2];
        #pragma unroll
        for (int i = 0; i < 2; i++)
            af[i] = *(const bf16x8*)(As + (size_t)cur * 2048 + (wm + i * 16 + l15) * 32 + rsw);
        #pragma unroll
        for (int j = 0; j < 2; j++)
            bfr[j] = *(const bf16x8*)(Bs + (size_t)cur * 2048 + (wn + j * 16 + l15) * 32 + rsw);
        #pragma unroll
        for (int i = 0; i < 2; i++)
            #pragma unroll
            for (int j = 0; j < 2; j++)
                acc[i][j] = __builtin_amdgcn_mfma_f32_16x16x32_bf16(af[i], bfr[j], acc[i][j], 0, 0, 0);
    }

    #pragma unroll
    for (int j = 0; j < 2; j++) {
        const int col = n0 + wn + j * 16 + l15;
        const float bv = bf2f(bo[col]);
        #pragma unroll
        for (int i = 0; i < 2; i++) {
            const int row = m0 + wm + i * 16 + quad * 4;
            #pragma unroll
            for (int r = 0; r < 4; r++)
                out[(size_t)(row + r) * DMODEL + col] = acc[i][j][r] + bv;
        }
    }
}

// ---------------- fused persistent kernel (cooperative launch) ----------------
__global__ __launch_bounds__(256, 3)
void fused_kernel(const float* __restrict__ q, const float* __restrict__ k,
                  const float* __restrict__ v,
                  const float* __restrict__ wqf, const float* __restrict__ bqf,
                  const float* __restrict__ wkf, const float* __restrict__ bkf,
                  const float* __restrict__ wvf, const float* __restrict__ bvf,
                  const float* __restrict__ wof, const float* __restrict__ bof,
                  float* __restrict__ out, unsigned short* __restrict__ ws)
{
    __shared__ __align__(16) unsigned char smem[49152];

    unsigned* ctr = (unsigned*)ws;                  // [0..2], memset by host
    unsigned short* wqb = ws + 3 * NQ;
    unsigned short* wkb = wqb + NW;
    unsigned short* wvb = wkb + NW;
    unsigned short* wob = wvb + NW;
    unsigned short* bqb = wob + NW;
    unsigned short* bkb = bqb + NB;
    unsigned short* bvb = bkb + NB;
    unsigned short* bob = bvb + NB;
    unsigned short* qh  = bob + NB;
    unsigned short* kh  = qh + NQ;
    unsigned short* vt  = kh + NQ;                  // [B,H,DK,S]
    unsigned short* ctx = vt + NQ;

    const int id = blockIdx.x;   // 0..767

    // ---- phase 0: cvt weights + biases (grid-strided) ----
    for (size_t i4 = ((size_t)id * 256 + threadIdx.x) * 4; i4 < CVTW_TOTAL;
         i4 += (size_t)gridDim.x * 256 * 4) {
        const float* src; size_t off;
        if      (i4 <     NW)          { src = wqf; off = i4; }
        else if (i4 < 2 * NW)          { src = wkf; off = i4 - NW; }
        else if (i4 < 3 * NW)          { src = wvf; off = i4 - 2 * NW; }
        else if (i4 < 4 * NW)          { src = wof; off = i4 - 3 * NW; }
        else if (i4 < 4 * NW + NB)     { src = bqf; off = i4 - 4 * NW; }
        else if (i4 < 4 * NW + 2 * NB) { src = bkf; off = i4 - 4 * NW - NB; }
        else if (i4 < 4 * NW + 3 * NB) { src = bvf; off = i4 - 4 * NW - 2 * NB; }
        else                           { src = bof; off = i4 - 4 * NW - 3 * NB; }
        const float4 f = *(const float4*)(src + off);
        ushort4 o;
        o.x = f2bf(f.x); o.y = f2bf(f.y); o.z = f2bf(f.z); o.w = f2bf(f.w);
        *(ushort4*)(wqb + i4) = o;
    }
    gbar(ctr + 0);

    // ---- phase 1: qkv gemm (768 jobs = 64 mtiles x 4 ntiles x 3 mats) ----
    {
        const int x = id & 63, y = (id >> 6) & 3, z = id >> 8;
        const float*          Az = (z == 0) ? q   : (z == 1) ? k   : v;
        const unsigned short* Wz = (z == 0) ? wqb : (z == 1) ? wkb : wvb;
        const unsigned short* Bz = (z == 0) ? bqb : (z == 1) ? bkb : bvb;
        unsigned short*       Cz = (z == 0) ? qh  : (z == 1) ? kh  : vt;
        qkv_body(Az, Wz, Bz, Cz, z, x * 128, y * 128, smem);
    }
    gbar(ctr + 1);

    // ---- phase 2: attention (1024 jobs over 768 blocks, per-CU = 66 iters:
    //      block c: (31-a, 16+a) = 49; c+256: 15-a -> 16-a; c+512: a -> a+1) ----
    {
        const int a = id >> 5, bh = id & 31;
        const int qt0 = (a < 8) ? 31 - a : (a < 16) ? 23 - a : a - 16;
        attn_body(qh, kh, vt, ctx, bh, qt0, smem);
        if (id < 256) {
            __syncthreads();   // LDS reuse between jobs
            attn_body(qh, kh, vt, ctx, bh, 16 + a, smem);
        }
    }
    gbar(ctr + 2);

    // ---- phase 3: oproj (1024 jobs = 128 mtiles x 8 ntiles over 768 blocks) ----
    {
        oproj_body(ctx, wob, bob, out, (id >> 3) * 64, (id & 7) * 64, smem);
        if (id < 256) {
            __syncthreads();   // LDS reuse between jobs
            const int j = id + 768;
            oproj_body(ctx, wob, bob, out, (j >> 3) * 64, (j & 7) * 64, smem);
        }
    }
}

// ---------------- fallback kernels (plain launches, no grid barriers) ----------------
__global__ __launch_bounds__(256)
void cvt_w_kernel(const float* __restrict__ wq, const float* __restrict__ wk,
                  const float* __restrict__ wv, const float* __restrict__ wo,
                  const float* __restrict__ bq, const float* __restrict__ bk,
                  const float* __restrict__ bv, const float* __restrict__ bo,
                  unsigned short* __restrict__ dst)   // dst = wqb base
{
    const size_t i4 = ((size_t)blockIdx.x * 256 + threadIdx.x) * 4;
    if (i4 >= CVTW_TOTAL) return;
    const float* src;
    size_t off;
    if      (i4 <     NW)          { src = wq; off = i4; }
    else if (i4 < 2 * NW)          { src = wk; off = i4 - NW; }
    else if (i4 < 3 * NW)          { src = wv; off = i4 - 2 * NW; }
    else if (i4 < 4 * NW)          { src = wo; off = i4 - 3 * NW; }
    else if (i4 < 4 * NW + NB)     { src = bq; off = i4 - 4 * NW; }
    else if (i4 < 4 * NW + 2 * NB) { src = bk; off = i4 - 4 * NW - NB; }
    else if (i4 < 4 * NW + 3 * NB) { src = bv; off = i4 - 4 * NW - 2 * NB; }
    else                           { src = bo; off = i4 - 4 * NW - 3 * NB; }
    const float4 f = *(const float4*)(src + off);
    ushort4 o;
    o.x = f2bf(f.x); o.y = f2bf(f.y); o.z = f2bf(f.z); o.w = f2bf(f.w);
    *(ushort4*)(dst + i4) = o;
}

__global__ __launch_bounds__(256, 3)
void qkv_gemm_kernel(const float* __restrict__ qin, const float* __restrict__ kin,
                     const float* __restrict__ vin,
                     const unsigned short* __restrict__ wq, const unsigned short* __restrict__ bq,
                     const unsigned short* __restrict__ wk, const unsigned short* __restrict__ bk,
                     const unsigned short* __restrict__ wv, const unsigned short* __restrict__ bv,
                     unsigned short* __restrict__ qh, unsigned short* __restrict__ kh,
                     unsigned short* __restrict__ vt)
{
    __shared__ __align__(16) unsigned char smem[49152];
    const int z = blockIdx.z;
    const float*          A    = (z == 0) ? qin : (z == 1) ? kin : vin;
    const unsigned short* W    = (z == 0) ? wq  : (z == 1) ? wk  : wv;
    const unsigned short* bias = (z == 0) ? bq  : (z == 1) ? bk  : bv;
    unsigned short*       C    = (z == 0) ? qh  : (z == 1) ? kh  : vt;
    qkv_body(A, W, bias, C, z, blockIdx.x * 128, blockIdx.y * 128, smem);
}

__global__ __launch_bounds__(256, 4)
void attn_kernel(const unsigned short* __restrict__ qh,
                 const unsigned short* __restrict__ kh,
                 const unsigned short* __restrict__ vt,
                 unsigned short* __restrict__ ctx)
{
    __shared__ __align__(16) unsigned char smem[40960];
    const int bh = blockIdx.x;
    const int x  = blockIdx.y;
    const int g  = x & 7, s = x >> 3;
    const int qt = (s == 0) ? g : (s == 1) ? 15 - g : (s == 2) ? 16 + g : 31 - g;
    attn_body(qh, kh, vt, ctx, bh, qt, smem);
}

__global__ __launch_bounds__(256, 4)
void oproj_gemm_kernel(const unsigned short* __restrict__ ctx,
                       const unsigned short* __restrict__ wo,
                       const unsigned short* __restrict__ bo,
                       float* __restrict__ out)
{
    __shared__ __align__(16) unsigned char smem[16384];
    oproj_body(ctx, wo, bo, out, blockIdx.x * 64, blockIdx.y * 64, smem);
}

extern "C" void kernel_launch(void* const* d_in, const int* in_sizes, int n_in,
                              void* d_out, int out_size, void* d_ws, size_t ws_size,
                              hipStream_t stream)
{
    const float* q   = (const float*)d_in[0];
    const float* k   = (const float*)d_in[1];
    const float* v   = (const float*)d_in[2];
    // d_in[3] = causal mask (int32) — causality implemented directly
    const float* w_q = (const float*)d_in[4];
    const float* b_q = (const float*)d_in[5];
    const float* w_k = (const float*)d_in[6];
    const float* b_k = (const float*)d_in[7];
    const float* w_v = (const float*)d_in[8];
    const float* b_v = (const float*)d_in[9];
    const float* w_o = (const float*)d_in[10];
    const float* b_o = (const float*)d_in[11];
    float* out = (float*)d_out;
    unsigned short* ws = (unsigned short*)d_ws;

    // zero the phase counters (graph-capturable async memset)
    hipMemsetAsync(ws, 0, 128, stream);

    void* args[] = {
        (void*)&q, (void*)&k, (void*)&v,
        (void*)&w_q, (void*)&b_q, (void*)&w_k, (void*)&b_k,
        (void*)&w_v, (void*)&b_v, (void*)&w_o, (void*)&b_o,
        (void*)&out, (void*)&ws
    };
    hipError_t rc = hipLaunchCooperativeKernel((const void*)fused_kernel,
                                               dim3(GRID_P), dim3(256),
                                               args, 0, stream);
    if (rc != hipSuccess) {
        // fallback: verified 4-kernel chain (same device bodies, no grid barriers)
        unsigned short* wqb = ws + 3 * NQ;
        unsigned short* wkb = wqb + NW;
        unsigned short* wvb = wkb + NW;
        unsigned short* wob = wvb + NW;
        unsigned short* bqb = wob + NW;
        unsigned short* bkb = bqb + NB;
        unsigned short* bvb = bkb + NB;
        unsigned short* bob = bvb + NB;
        unsigned short* qh  = bob + NB;
        unsigned short* kh  = qh + NQ;
        unsigned short* vt  = kh + NQ;
        unsigned short* ctx = vt + NQ;

        dim3 blk(256);
        hipLaunchKernelGGL(cvt_w_kernel, dim3((unsigned)(CVTW_TOTAL / 4 / 256)), blk, 0, stream,
                           w_q, w_k, w_v, w_o, b_q, b_k, b_v, b_o, wqb);
        hipLaunchKernelGGL(qkv_gemm_kernel, dim3(MROWS / 128, DMODEL / 128, 3), blk, 0, stream,
                           q, k, v, wqb, bqb, wkb, bkb, wvb, bvb, qh, kh, vt);
        hipLaunchKernelGGL(attn_kernel, dim3(BATCH * NHEAD, 32), blk, 0, stream,
                           qh, kh, vt, ctx);
        hipLaunchKernelGGL(oproj_gemm_kernel, dim3(MROWS / 64, DMODEL / 64), blk, 0, stream,
                           ctx, wob, bob, out);
    }
}

// Round 6
// 193.963 us; speedup vs baseline: 3.5897x; 3.5897x over previous
//
#include <hip/hip_runtime.h>
#include <hip/hip_bf16.h>

// MultiHeadAttentionBlock: B=4, S=2048, D=512, H=8, DK=64, causal.
// R16: plain 4-kernel chain (fusion abandoned).
//   Evidence: R15's cooperative fused kernel ran CORRECTLY but 3x slower
//   (600us, MfmaUtil 2.3%): 768 blocks acquire-spinning one agent-scope
//   line costs ~170us per grid barrier (cross-XCD coherence point
//   serializes the pollers). Also, comparing GPU-busy vs dur_us across
//   R0/R3/R5: harness overhead is ~95us FIXED regardless of launch count
//   (5, 4, or 2 launches) -> the "inter-dispatch gap" premise of R13-R15
//   was wrong; only summed kernel GPU time matters.
//   This round: keep the two verified GPU-time wins from the R5 bodies
//   (they passed numerically inside the fused run):
//   (1) qkv GEMM stages A fp32 DIRECTLY via global_load_lds, bf16 convert
//       at LDS-read (kills the 72MB activation-cvt round-trip, no R13
//       write-side serialization);
//   (2) oproj 64x64 4-wave tiles, 1024 blocks = 4/CU.
//   attn = R10 structure (best measured ~49.4us), cvt = weights/bias only.

#define BATCH  4
#define SLEN   2048
#define DMODEL 512
#define NHEAD  8
#define DHEAD  64
#define MROWS  (BATCH * SLEN)   // 8192

#define NQ ((size_t)MROWS * DMODEL)     // 4194304
#define NW ((size_t)DMODEL * DMODEL)    // 262144
#define NB ((size_t)DMODEL)             // 512
#define CVTW_TOTAL (4 * NW + 4 * NB)    // 1050624

#define SCALE_L2E 0.180336880f          // (1/8) * log2(e)

typedef short bf16x8 __attribute__((ext_vector_type(8)));
typedef float f32x4  __attribute__((ext_vector_type(4)));

typedef unsigned int __attribute__((address_space(1))) glb_u32_t;
typedef unsigned int __attribute__((address_space(3))) lds_u32_t;

__device__ __forceinline__ void async16(const void* g, void* l) {
    // 16B per lane, HW writes LDS at wave-uniform base + lane*16
    __builtin_amdgcn_global_load_lds((glb_u32_t*)g, (lds_u32_t*)l, 16, 0, 0);
}

__device__ __forceinline__ float bf2f(unsigned short u) {
    union { unsigned int i; float f; } v; v.i = ((unsigned int)u) << 16; return v.f;
}
__device__ __forceinline__ unsigned short f2bf(float f) {
    union { float f; unsigned int i; } v; v.f = f;
    unsigned int x = v.i;
    return (unsigned short)((x + 0x7fffu + ((x >> 16) & 1u)) >> 16);
}
__device__ __forceinline__ unsigned int pkbf(float a, float b) {
    union { __hip_bfloat162 h; unsigned int u; } cv;
    cv.h = __float22bfloat162_rn(float2{a, b});
    return cv.u;
}

__device__ __forceinline__ void wait0_barrier() {
    asm volatile("s_waitcnt vmcnt(0)" ::: "memory");
    __builtin_amdgcn_s_barrier();
    asm volatile("" ::: "memory");
}

// ---------------- cvt: WEIGHTS + BIASES only (4.2MB) ----------------
__global__ __launch_bounds__(256)
void cvt_w_kernel(const float* __restrict__ wq, const float* __restrict__ wk,
                  const float* __restrict__ wv, const float* __restrict__ wo,
                  const float* __restrict__ bq, const float* __restrict__ bk,
                  const float* __restrict__ bv, const float* __restrict__ bo,
                  unsigned short* __restrict__ dst)   // dst = wqb base
{
    const size_t i4 = ((size_t)blockIdx.x * 256 + threadIdx.x) * 4;
    if (i4 >= CVTW_TOTAL) return;
    const float* src;
    size_t off;
    if      (i4 <     NW)          { src = wq; off = i4; }
    else if (i4 < 2 * NW)          { src = wk; off = i4 - NW; }
    else if (i4 < 3 * NW)          { src = wv; off = i4 - 2 * NW; }
    else if (i4 < 4 * NW)          { src = wo; off = i4 - 3 * NW; }
    else if (i4 < 4 * NW + NB)     { src = bq; off = i4 - 4 * NW; }
    else if (i4 < 4 * NW + 2 * NB) { src = bk; off = i4 - 4 * NW - NB; }
    else if (i4 < 4 * NW + 3 * NB) { src = bv; off = i4 - 4 * NW - 2 * NB; }
    else                           { src = bo; off = i4 - 4 * NW - 3 * NB; }
    const float4 f = *(const float4*)(src + off);
    ushort4 o;
    o.x = f2bf(f.x); o.y = f2bf(f.y); o.z = f2bf(f.z); o.w = f2bf(f.w);
    *(ushort4*)(dst + i4) = o;
}

// ---------------- qkv GEMM body: C[M,512] = A_fp32 * W_bf16^T + b ----------------
// 128x128 tile, BK=32, 4 waves -> 64x64 each. A staged fp32 via gload_lds
// (dbuf 32KB, rows of 8 16B-chunks, phys = logical ^ (row&7)); converted to
// bf16 at LDS-read. W bf16 via gload_lds (rows of 4 chunks, phys = logical ^
// (row&3)). One barrier per K-iter. mode: 0=Q(scaled) 1=K 2=V^T store.
// [verified numerically in R15's fused run]
__device__ __forceinline__ void qkv_body(const float* __restrict__ A,
                                         const unsigned short* __restrict__ W,
                                         const unsigned short* __restrict__ bias,
                                         unsigned short* __restrict__ C,
                                         int mode, int m0, int n0,
                                         unsigned char* smem)
{
    float*          Asf = (float*)smem;                          // [2][128*32] f32 32KB
    unsigned short* Bs  = (unsigned short*)(smem + 32768);       // [2][128*32] bf16 16KB

    const int tid  = threadIdx.x;
    const int wave = tid >> 6;
    const int lane = tid & 63;
    const int l15  = lane & 15;
    const int quad = lane >> 4;
    const int wm   = (wave & 1) * 64;
    const int wn   = (wave >> 1) * 64;
    const int srow = lane >> 2;                         // W staging: 0..15
    const int scol = (((lane & 3) ^ (srow & 3)) * 8);   // W swizzled col (bf16)
    const int rswb = (quad ^ (l15 & 3)) * 8;            // W read swizzle
    const int krow = lane >> 3;                         // A staging: 0..7
    const int acol = ((lane & 7) ^ (krow & 7)) * 4;     // A swizzled col (f32)

    auto stageA = [&](int k0, int buf) {
        #pragma unroll
        for (int c = 0; c < 4; c++) {
            const int rb = c * 32 + wave * 8;
            async16(A + (size_t)(m0 + rb + krow) * DMODEL + k0 + acol,
                    Asf + (size_t)buf * 4096 + rb * 32);
        }
    };
    auto stageW = [&](int k0, int buf) {
        async16(W + (size_t)(n0 + wave * 16 + srow) * DMODEL + k0 + scol,
                Bs + (size_t)buf * 4096 + wave * 512);
        async16(W + (size_t)(n0 + (wave + 4) * 16 + srow) * DMODEL + k0 + scol,
                Bs + (size_t)buf * 4096 + (wave + 4) * 512);
    };

    f32x4 acc[4][4] = {};
    stageA(0, 0);
    stageW(0, 0);

    #pragma unroll 1
    for (int kt = 0; kt < 16; kt++) {
        const int cur = kt & 1;
        wait0_barrier();
        if (kt < 15) { stageA((kt + 1) * 32, cur ^ 1); stageW((kt + 1) * 32, cur ^ 1); }

        bf16x8 af[4], bfr[4];
        #pragma unroll
        for (int i = 0; i < 4; i++) {
            const int row = wm + i * 16 + l15;
            const float* rp = Asf + (size_t)cur * 4096 + row * 32;
            const f32x4 x = *(const f32x4*)(rp + (((quad * 2)     ^ (row & 7)) * 4));
            const f32x4 y = *(const f32x4*)(rp + (((quad * 2 + 1) ^ (row & 7)) * 4));
            union { bf16x8 v; unsigned int u[4]; } r;
            r.u[0] = pkbf(x[0], x[1]); r.u[1] = pkbf(x[2], x[3]);
            r.u[2] = pkbf(y[0], y[1]); r.u[3] = pkbf(y[2], y[3]);
            af[i] = r.v;
        }
        #pragma unroll
        for (int j = 0; j < 4; j++)
            bfr[j] = *(const bf16x8*)(Bs + (size_t)cur * 4096 + (wn + j * 16 + l15) * 32 + rswb);
        #pragma unroll
        for (int i = 0; i < 4; i++)
            #pragma unroll
            for (int j = 0; j < 4; j++)
                acc[i][j] = __builtin_amdgcn_mfma_f32_16x16x32_bf16(af[i], bfr[j], acc[i][j], 0, 0, 0);
    }

    // epilogue: C/D layout col = lane&15, row = quad*4 + reg
    if (mode == 2) {
        // V^T store: col -> (h,dk), row -> (b,s)
        #pragma unroll
        for (int j = 0; j < 4; j++) {
            const int col = n0 + wn + j * 16 + l15;
            const float bv = bf2f(bias[col]);
            const int hh = col >> 6, dk = col & 63;
            #pragma unroll
            for (int i = 0; i < 4; i++) {
                const int row = m0 + wm + i * 16 + quad * 4;
                const int bb = row >> 11, s = row & 2047;
                uint2 o2;
                o2.x = pkbf(acc[i][j][0] + bv, acc[i][j][1] + bv);
                o2.y = pkbf(acc[i][j][2] + bv, acc[i][j][3] + bv);
                *(uint2*)(C + ((size_t)((bb * NHEAD + hh) * DHEAD + dk)) * SLEN + s) = o2;
            }
        }
    } else {
        const float oscale = (mode == 0) ? SCALE_L2E : 1.0f;
        #pragma unroll
        for (int j = 0; j < 4; j++) {
            const int col = n0 + wn + j * 16 + l15;
            const float bv = bf2f(bias[col]);
            #pragma unroll
            for (int i = 0; i < 4; i++) {
                const int row = m0 + wm + i * 16 + quad * 4;
                #pragma unroll
                for (int r = 0; r < 4; r++)
                    C[(size_t)(row + r) * DMODEL + col] = f2bf((acc[i][j][r] + bv) * oscale);
            }
        }
    }
}

__global__ __launch_bounds__(256, 3)
void qkv_gemm_kernel(const float* __restrict__ qin, const float* __restrict__ kin,
                     const float* __restrict__ vin,
                     const unsigned short* __restrict__ wq, const unsigned short* __restrict__ bq,
                     const unsigned short* __restrict__ wk, const unsigned short* __restrict__ bk,
                     const unsigned short* __restrict__ wv, const unsigned short* __restrict__ bv,
                     unsigned short* __restrict__ qh, unsigned short* __restrict__ kh,
                     unsigned short* __restrict__ vt)
{
    __shared__ __align__(16) unsigned char smem[49152];
    const int z = blockIdx.z;
    const float*          A    = (z == 0) ? qin : (z == 1) ? kin : vin;
    const unsigned short* W    = (z == 0) ? wq  : (z == 1) ? wk  : wv;
    const unsigned short* bias = (z == 0) ? bq  : (z == 1) ? bk  : bv;
    unsigned short*       C    = (z == 0) ? qh  : (z == 1) ? kh  : vt;
    qkv_body(A, W, bias, C, z, blockIdx.x * 128, blockIdx.y * 128, smem);
}

// ---------------- Flash attention body (R10 inner structure) ----------------
// One 64-row q-tile of one (b,h); 4 waves x 16 q. KV tiles of 64 staged via
// gload_lds into XOR-chunk-swizzled double buffers; one barrier/iter.
// Q pre-scaled by (1/8)log2e; fixed-reference softmax p = exp2(s).
// LDS: Ks 16K + Vs 16K + Ps 8K = 40960 B -> 4 blocks/CU.
// [verified numerically in R15's fused run; best measured ~49.4us as R10]
__device__ __forceinline__ void attn_body(const unsigned short* __restrict__ qh,
                                          const unsigned short* __restrict__ kh,
                                          const unsigned short* __restrict__ vt,
                                          unsigned short* __restrict__ ctx,
                                          int bh, int qt, unsigned char* smem)
{
    unsigned short* Ks = (unsigned short*)smem;       // [2][64*64]
    unsigned short* Vs = Ks + 2 * 64 * 64;            // [2][64*64]
    unsigned short* Ps = Vs + 2 * 64 * 64;            // [4][16*64]

    const int tid  = threadIdx.x;
    const int wave = tid >> 6;
    const int lane = tid & 63;
    const int l15  = lane & 15;
    const int quad = lane >> 4;
    const int b = bh >> 3, h = bh & 7;

    const size_t base = (size_t)b * SLEN * DMODEL + (size_t)h * DHEAD;
    const unsigned short* Q  = qh + base;
    const unsigned short* K  = kh + base;
    const unsigned short* VT = vt + (size_t)bh * DHEAD * SLEN;

    const int krow_l = lane >> 3;
    const int kcol_l = ((lane & 7) ^ (krow_l & 7)) * 8;

    const int qrow = qt * 64 + wave * 16 + l15;
    const bf16x8 qf0 = *(const bf16x8*)(Q + (size_t)qrow * DMODEL + quad * 8);
    const bf16x8 qf1 = *(const bf16x8*)(Q + (size_t)qrow * DMODEL + 32 + quad * 8);

    f32x4 oacc[4] = {};
    float lsum = 0.0f;
    unsigned short* Pw = Ps + wave * (16 * 64);
    const int ktiles = qt + 1;

    auto stageKV = [&](int kt, int buf) {
        async16(K + (size_t)(kt * 64 + wave * 8 + krow_l) * DMODEL + kcol_l,
                Ks + (size_t)buf * 4096 + wave * 512);
        async16(K + (size_t)(kt * 64 + (wave + 4) * 8 + krow_l) * DMODEL + kcol_l,
                Ks + (size_t)buf * 4096 + (wave + 4) * 512);
        async16(VT + (size_t)(wave * 8 + krow_l) * SLEN + kt * 64 + kcol_l,
                Vs + (size_t)buf * 4096 + wave * 512);
        async16(VT + (size_t)((wave + 4) * 8 + krow_l) * SLEN + kt * 64 + kcol_l,
                Vs + (size_t)buf * 4096 + (wave + 4) * 512);
    };

    stageKV(0, 0);

    #pragma unroll 1
    for (int kt = 0; kt < ktiles; kt++) {
        const int cur = kt & 1;
        wait0_barrier();
        if (kt + 1 < ktiles) stageKV(kt + 1, cur ^ 1);

        // S^T = K Q^T
        f32x4 sacc[4] = {};
        #pragma unroll
        for (int kk = 0; kk < 2; kk++) {
            const bf16x8 qf = kk ? qf1 : qf0;
            #pragma unroll
            for (int j = 0; j < 4; j++) {
                bf16x8 kf = *(const bf16x8*)(Ks + (size_t)cur * 4096 + (j * 16 + l15) * 64
                                                + (((kk * 4 + quad) ^ (l15 & 7)) * 8));
                sacc[j] = __builtin_amdgcn_mfma_f32_16x16x32_bf16(kf, qf, sacc[j], 0, 0, 0);
            }
        }

        if (kt == qt) {   // causal mask: diagonal tile only
            #pragma unroll
            for (int j = 0; j < 4; j++)
                #pragma unroll
                for (int r = 0; r < 4; r++) {
                    const int kv = kt * 64 + j * 16 + quad * 4 + r;
                    if (kv > qrow) sacc[j][r] = -1e30f;
                }
        }

        // p = exp2(s); accumulate l; pack P^T -> Ps[q][kv] (XOR chunk swizzle)
        #pragma unroll
        for (int j = 0; j < 4; j++) {
            const float p0 = exp2f(sacc[j][0]);
            const float p1 = exp2f(sacc[j][1]);
            const float p2v = exp2f(sacc[j][2]);
            const float p3 = exp2f(sacc[j][3]);
            lsum += (p0 + p1) + (p2v + p3);
            uint2 pw;
            pw.x = pkbf(p0, p1);
            pw.y = pkbf(p2v, p3);
            const int chunk = (j * 2 + (quad >> 1)) ^ (l15 & 7);
            *(uint2*)(Pw + l15 * 64 + chunk * 8 + (quad & 1) * 4) = pw;
        }
        asm volatile("s_waitcnt lgkmcnt(0)" ::: "memory");   // same-wave P round-trip

        // O^T += V^T P^T
        #pragma unroll
        for (int kk = 0; kk < 2; kk++) {
            bf16x8 pf = *(const bf16x8*)(Pw + l15 * 64 + (((kk * 4 + quad) ^ (l15 & 7)) * 8));
            #pragma unroll
            for (int jd = 0; jd < 4; jd++) {
                bf16x8 vf = *(const bf16x8*)(Vs + (size_t)cur * 4096 + (jd * 16 + l15) * 64
                                                + (((kk * 4 + quad) ^ (l15 & 7)) * 8));
                oacc[jd] = __builtin_amdgcn_mfma_f32_16x16x32_bf16(vf, pf, oacc[jd], 0, 0, 0);
            }
        }
    }

    lsum += __shfl_xor(lsum, 16, 64);
    lsum += __shfl_xor(lsum, 32, 64);
    const float invl = 1.0f / lsum;

    #pragma unroll
    for (int jd = 0; jd < 4; jd++) {
        uint2 o2;
        o2.x = pkbf(oacc[jd][0] * invl, oacc[jd][1] * invl);
        o2.y = pkbf(oacc[jd][2] * invl, oacc[jd][3] * invl);
        *(uint2*)(ctx + base + (size_t)qrow * DMODEL + jd * 16 + quad * 4) = o2;
    }
}

__global__ __launch_bounds__(256, 4)
void attn_kernel(const unsigned short* __restrict__ qh,
                 const unsigned short* __restrict__ kh,
                 const unsigned short* __restrict__ vt,
                 unsigned short* __restrict__ ctx)
{
    __shared__ __align__(16) unsigned char smem[40960];
    const int bh = blockIdx.x;        // head-major: bh%8 -> XCD K/V L2 locality
    const int x  = blockIdx.y;        // 0..31
    const int g  = x & 7, s = x >> 3; // balanced classes: per-CU iters = 66
    const int qt = (s == 0) ? g : (s == 1) ? 15 - g : (s == 2) ? 16 + g : 31 - g;
    attn_body(qh, kh, vt, ctx, bh, qt, smem);
}

// ---------------- oproj body: out[M,512] = ctx_bf16 * Wo^T + bo ----------------
// 64x64 tile, 4 waves -> 32x32 each. LDS 16KB dbuf, gload_lds, XOR swizzle.
// 1024 blocks = 4/CU. [verified numerically in R15's fused run]
__device__ __forceinline__ void oproj_body(const unsigned short* __restrict__ ctx,
                                           const unsigned short* __restrict__ wo,
                                           const unsigned short* __restrict__ bo,
                                           float* __restrict__ out,
                                           int m0, int n0, unsigned char* smem)
{
    unsigned short* As = (unsigned short*)smem;   // [2][64*32]
    unsigned short* Bs = As + 2 * 64 * 32;        // [2][64*32]

    const int tid  = threadIdx.x;
    const int wave = tid >> 6;
    const int lane = tid & 63;
    const int l15  = lane & 15;
    const int quad = lane >> 4;
    const int wm   = (wave & 1) * 32;
    const int wn   = (wave >> 1) * 32;
    const int srow = lane >> 2;
    const int scol = (((lane & 3) ^ (srow & 3)) * 8);
    const int rsw  = (quad ^ (l15 & 3)) * 8;

    auto stage = [&](int k0, int buf) {
        async16(ctx + (size_t)(m0 + wave * 16 + srow) * DMODEL + k0 + scol,
                As + (size_t)buf * 2048 + wave * 512);
        async16(wo + (size_t)(n0 + wave * 16 + srow) * DMODEL + k0 + scol,
                Bs + (size_t)buf * 2048 + wave * 512);
    };

    f32x4 acc[2][2] = {};
    stage(0, 0);

    #pragma unroll 1
    for (int kt = 0; kt < 16; kt++) {
        const int cur = kt & 1;
        wait0_barrier();
        if (kt < 15) stage((kt + 1) * 32, cur ^ 1);

        bf16x8 af[2], bfr[2];
        #pragma unroll
        for (int i = 0; i < 2; i++)
            af[i] = *(const bf16x8*)(As + (size_t)cur * 2048 + (wm + i * 16 + l15) * 32 + rsw);
        #pragma unroll
        for (int j = 0; j < 2; j++)
            bfr[j] = *(const bf16x8*)(Bs + (size_t)cur * 2048 + (wn + j * 16 + l15) * 32 + rsw);
        #pragma unroll
        for (int i = 0; i < 2; i++)
            #pragma unroll
            for (int j = 0; j < 2; j++)
                acc[i][j] = __builtin_amdgcn_mfma_f32_16x16x32_bf16(af[i], bfr[j], acc[i][j], 0, 0, 0);
    }

    #pragma unroll
    for (int j = 0; j < 2; j++) {
        const int col = n0 + wn + j * 16 + l15;
        const float bv = bf2f(bo[col]);
        #pragma unroll
        for (int i = 0; i < 2; i++) {
            const int row = m0 + wm + i * 16 + quad * 4;
            #pragma unroll
            for (int r = 0; r < 4; r++)
                out[(size_t)(row + r) * DMODEL + col] = acc[i][j][r] + bv;
        }
    }
}

__global__ __launch_bounds__(256, 4)
void oproj_gemm_kernel(const unsigned short* __restrict__ ctx,
                       const unsigned short* __restrict__ wo,
                       const unsigned short* __restrict__ bo,
                       float* __restrict__ out)
{
    __shared__ __align__(16) unsigned char smem[16384];
    oproj_body(ctx, wo, bo, out, blockIdx.x * 64, blockIdx.y * 64, smem);
}

extern "C" void kernel_launch(void* const* d_in, const int* in_sizes, int n_in,
                              void* d_out, int out_size, void* d_ws, size_t ws_size,
                              hipStream_t stream)
{
    const float* q   = (const float*)d_in[0];
    const float* k   = (const float*)d_in[1];
    const float* v   = (const float*)d_in[2];
    // d_in[3] = causal mask (int32) — causality implemented directly
    const float* w_q = (const float*)d_in[4];
    const float* b_q = (const float*)d_in[5];
    const float* w_k = (const float*)d_in[6];
    const float* b_k = (const float*)d_in[7];
    const float* w_v = (const float*)d_in[8];
    const float* b_v = (const float*)d_in[9];
    const float* w_o = (const float*)d_in[10];
    const float* b_o = (const float*)d_in[11];
    float* out = (float*)d_out;
    unsigned short* ws = (unsigned short*)d_ws;

    // bf16 workspace layout (elements); activation slots unused (A read fp32).
    unsigned short* wqb = ws + 3 * NQ;              // NW
    unsigned short* wkb = wqb + NW;
    unsigned short* wvb = wkb + NW;
    unsigned short* wob = wvb + NW;
    unsigned short* bqb = wob + NW;                 // NB
    unsigned short* bkb = bqb + NB;
    unsigned short* bvb = bkb + NB;
    unsigned short* bob = bvb + NB;
    unsigned short* qh  = bob + NB;                 // NQ each below
    unsigned short* kh  = qh + NQ;
    unsigned short* vt  = kh + NQ;                  // [B,H,DK,S]
    unsigned short* ctx = vt + NQ;

    dim3 blk(256);
    hipLaunchKernelGGL(cvt_w_kernel, dim3((unsigned)(CVTW_TOTAL / 4 / 256)), blk, 0, stream,
                       w_q, w_k, w_v, w_o, b_q, b_k, b_v, b_o, wqb);
    hipLaunchKernelGGL(qkv_gemm_kernel, dim3(MROWS / 128, DMODEL / 128, 3), blk, 0, stream,
                       q, k, v, wqb, bqb, wkb, bkb, wvb, bvb, qh, kh, vt);
    hipLaunchKernelGGL(attn_kernel, dim3(BATCH * NHEAD, 32), blk, 0, stream,
                       qh, kh, vt, ctx);
    hipLaunchKernelGGL(oproj_gemm_kernel, dim3(MROWS / 64, DMODEL / 64), blk, 0, stream,
                       ctx, wob, bob, out);
}